// Round 11
// baseline (1769.560 us; speedup 1.0000x reference)
//
#include <hip/hip_runtime.h>

// FHETinyGPT forward: emb-gather -> q/k/v proj -> QK^T+poly-act -> PV -> wo -> logits.
// Small/medium matmuls: m97-structure gemm_bt (128x128, BK=32, 4 waves).
// Logits GEMM: 256x256 8-wave, BK=64, 2 LDS buffers, register ping-pong: each
// phase issues ds_reads for the NEXT phase's fragments; MFMA consumes the set
// loaded one phase earlier (overlaps LDS latency with MFMA pipe). Counted vmcnt
// waits on the PRODUCER side (before the phase-end barrier) — R10-verified.
// R11: __launch_bounds__(512,1) (was (512,2)). The 2-waves/EU bound imposed a
// 128-VGPR cap; ping-pong needs ~210 (acc 128 + 2x frag sets 64 + addr) ->
// ~80 VGPRs spilled to scratch: R10 counters showed VGPR=128(cap), WRITE_SIZE
// +0.4GB / FETCH +0.12GB (scratch traffic), MfmaUtil 15%, VALU 9.8% (latency-
// bound). LDS=128KB already limits to 1 block/CU (2 waves/SIMD), which the
// VGPR file supports at 256 VGPRs/wave — the cap bought nothing.

typedef __bf16 bf16_t;
typedef __bf16 bf16x8 __attribute__((ext_vector_type(8)));
typedef __bf16 bf16x4 __attribute__((ext_vector_type(4)));
typedef float  f32x4  __attribute__((ext_vector_type(4)));

#define VOCAB 32000
#define DIM   1024
#define BATCH 4
#define SEQ   2048
#define BT    (BATCH*SEQ)   // 8192

__device__ __forceinline__ void gload_lds16(const void* g, void* l) {
    __builtin_amdgcn_global_load_lds(
        (const __attribute__((address_space(1))) void*)g,
        (__attribute__((address_space(3))) void*)l,
        16, 0, 0);
}

// ---------------- weight cast f32 -> bf16 ------------------------------------------
__global__ void cast_f32_to_bf16(const float* __restrict__ in, bf16_t* __restrict__ out, int n4) {
    int i = blockIdx.x * blockDim.x + threadIdx.x;
    if (i < n4) {
        float4 v = ((const float4*)in)[i];
        bf16x4 o;
        o.x = (bf16_t)v.x; o.y = (bf16_t)v.y; o.z = (bf16_t)v.z; o.w = (bf16_t)v.w;
        ((bf16x4*)out)[i] = o;
    }
}

// ---------------- h = emb_w[x] * 0.01 -> bf16 [BT, DIM] ----------------------------
__global__ void embed_gather(const int* __restrict__ x, const float* __restrict__ emb,
                             bf16_t* __restrict__ h) {
    const int tok = blockIdx.x;
    const int row = x[tok];
    const float4* src = (const float4*)(emb + (long)row * DIM);
    bf16x4* dst = (bf16x4*)(h + (long)tok * DIM);
    int j = threadIdx.x;
    float4 v = src[j];
    bf16x4 o;
    o.x = (bf16_t)(v.x * 0.01f); o.y = (bf16_t)(v.y * 0.01f);
    o.z = (bf16_t)(v.z * 0.01f); o.w = (bf16_t)(v.w * 0.01f);
    dst[j] = o;
}

// ---------------- gemm_bt (m97-structure, for the small/medium matmuls) ------------
template<int ACT, typename CT>
__global__ __launch_bounds__(256) void gemm_bt(
    const bf16_t* __restrict__ A, const bf16_t* __restrict__ B, CT* __restrict__ C,
    int M, int N, int K, long sA, long sB, long sC, float scale)
{
    __shared__ __align__(16) bf16_t lsA[128 * 32];
    __shared__ __align__(16) bf16_t lsB[128 * 32];

    const int bz = blockIdx.z;
    A += (long)bz * sA;  B += (long)bz * sB;  C += (long)bz * sC;

    const int tm = blockIdx.y, tn = blockIdx.x;
    const int t = threadIdx.x;
    const int lane = t & 63, wave = t >> 6;
    const int wm = (wave >> 1) * 64;
    const int wn = (wave & 1) * 64;

    const int srow = t >> 2;
    const int scol = (t & 3) * 8;
    const bf16_t* gA = A + (long)(tm * 128 + srow) * K + scol;
    const bf16_t* gB = B + (long)(tn * 128 + srow) * K + scol;
    bf16_t* lA = &lsA[srow * 32 + scol];
    bf16_t* lB = &lsB[srow * 32 + scol];

    f32x4 acc[4][4];
#pragma unroll
    for (int i = 0; i < 4; ++i)
#pragma unroll
        for (int j = 0; j < 4; ++j)
            acc[i][j] = (f32x4){0.f, 0.f, 0.f, 0.f};

    const int arow = lane & 15;
    const int acol = (lane >> 4) * 8;

    for (int k0 = 0; k0 < K; k0 += 32) {
        __syncthreads();
        gload_lds16(gA + k0,                lA);
        gload_lds16(gA + k0 + 64 * (long)K, lA + 64 * 32);
        gload_lds16(gB + k0,                lB);
        gload_lds16(gB + k0 + 64 * (long)K, lB + 64 * 32);
        __syncthreads();

        bf16x8 af[4], bfr[4];
#pragma unroll
        for (int i = 0; i < 4; ++i) {
            af[i]  = *(const bf16x8*)&lsA[(wm + i * 16 + arow) * 32 + acol];
            bfr[i] = *(const bf16x8*)&lsB[(wn + i * 16 + arow) * 32 + acol];
        }
#pragma unroll
        for (int i = 0; i < 4; ++i)
#pragma unroll
            for (int j = 0; j < 4; ++j)
                acc[i][j] = __builtin_amdgcn_mfma_f32_16x16x32_bf16(af[i], bfr[j], acc[i][j], 0, 0, 0);
    }

    const int crow0 = tm * 128 + wm + (lane >> 4) * 4;
    const int ccol0 = tn * 128 + wn + (lane & 15);
#pragma unroll
    for (int i = 0; i < 4; ++i)
#pragma unroll
        for (int j = 0; j < 4; ++j)
#pragma unroll
            for (int r = 0; r < 4; ++r) {
                float s = acc[i][j][r] * scale;
                if (ACT) s = s * s * 0.1f + s * 0.1f;
                C[(long)(crow0 + i * 16 + r) * N + (ccol0 + j * 16)] = (CT)s;
            }
}

// ---------------- 256x256 pipelined GEMM: C[M,N] = scale * A[M,K] @ B[N,K]^T -------
// Requires: M == 8192 (32 M-tiles, band swizzle), N % 256 == 0, K % 128 == 0.
// Grid: 1-D, (M/256)*(N/256) blocks of 512 threads.
__global__ __launch_bounds__(512, 1) void gemm_bt_256(
    const bf16_t* __restrict__ A, const bf16_t* __restrict__ B, float* __restrict__ C,
    int N, int K, float scale)
{
    __shared__ __align__(16) char smem[131072];   // 2buf x (A 32KB + B 32KB)
    char* const sm = smem;

    // band swizzle: XCD k owns tm in [4k, 4k+4); tm-inner-4, tn-outer.
    const int lin = blockIdx.x;
    const int xcd = lin & 7, jj = lin >> 3;
    const int tm = xcd * 4 + (jj & 3);
    const int tn = jj >> 2;
    const long trow0 = (long)tm * 256, tcol0 = (long)tn * 256;

    const int tid  = threadIdx.x;
    const int lane = tid & 63;
    const int wave = tid >> 6;
    const int wm = wave >> 2;            // 0..1  (M sub-band within each 128-half)
    const int wn = wave & 3;             // 0..3
    const int lr = lane & 15;
    const int ko2 = (lane >> 4) * 16;    // byte offset of this lane's 16B k-chunk
    // swizzled per-thread byte offset within a 1KB subtile (involution on bits 4-5)
    const int rbase = lr * 64 + (ko2 ^ (((lr >> 1) & 3) << 4));

    // staging decode (R4-verified): physical slot o holds logical slot sigma(o)
    const int o0 = tid * 16, o1 = 8192 + tid * 16;
    int sr0, sc0, sr1, sc1;
    {
        int ol = o0 ^ (((o0 >> 7) & 3) << 4);
        sr0 = ((ol >> 10) >> 1) * 16 + ((ol >> 6) & 15);
        sc0 = ((ol >> 10) & 1) * 32 + ((ol & 63) >> 1);
        ol = o1 ^ (((o1 >> 7) & 3) << 4);
        sr1 = ((ol >> 10) >> 1) * 16 + ((ol >> 6) & 15);
        sc1 = ((ol >> 10) & 1) * 32 + ((ol & 63) >> 1);
    }

    const bf16_t* Abase = A + trow0 * K;
    const bf16_t* Bbase = B + tcol0 * K;

    // stage one half-tile (128 rows x 64 cols) of K-tile kt into LDS half at ldsh
#define STAGE_HT(gbase, kt, half, ldsh) do {                                          \
    gload_lds16((gbase) + (long)((half) * 128 + sr0) * K + ((kt) * 64 + sc0), (ldsh) + o0); \
    gload_lds16((gbase) + (long)((half) * 128 + sr1) * K + ((kt) * 64 + sc1), (ldsh) + o1); \
} while (0)

    f32x4 acc[8][4];
#pragma unroll
    for (int i = 0; i < 8; ++i)
#pragma unroll
        for (int j = 0; j < 4; ++j)
            acc[i][j] = (f32x4){0.f, 0.f, 0.f, 0.f};

    // fragment register sets (static names -> no scratch)
    bf16x8 af0[4], af1[4], bv0[4], bv1[4];

    // issue 4 A-frag reads: half h, k-step ks, from LDS-A base `base`
#define LD_A(dst, base, h, ks) do {                                                   \
    _Pragma("unroll")                                                                 \
    for (int i_ = 0; i_ < 4; ++i_)                                                    \
        dst[i_] = *(const bf16x8*)((base) + (h) * 16384 +                             \
                      ((wm * 4 + i_) * 2 + (ks)) * 1024 + rbase);                     \
} while (0)
    // issue 4 B-frag reads (both N-halves), k-step ks, from LDS-B base `base`
#define LD_B(dst, base, ks) do {                                                      \
    _Pragma("unroll")                                                                 \
    for (int c_ = 0; c_ < 4; ++c_)                                                    \
        dst[c_] = *(const bf16x8*)((base) + (c_ >> 1) * 16384 +                       \
                      ((wn * 2 + (c_ & 1)) * 2 + (ks)) * 1024 + rbase);               \
} while (0)
    // 16 MFMA into acc rows r0..r0+3 (compiler inserts counted lgkm waits on
    // first use of af/bv). No barrier — caller appends fence/waits/barrier.
#define MFMA16(r0, af, bv) do {                                                       \
    __builtin_amdgcn_s_setprio(1);                                                    \
    _Pragma("unroll")                                                                 \
    for (int i_ = 0; i_ < 4; ++i_)                                                    \
        _Pragma("unroll")                                                             \
        for (int c_ = 0; c_ < 4; ++c_)                                                \
            acc[(r0) + i_][c_] = __builtin_amdgcn_mfma_f32_16x16x32_bf16(             \
                af[i_], bv[c_], acc[(r0) + i_][c_], 0, 0, 0);                         \
    __builtin_amdgcn_s_setprio(0);                                                    \
    __builtin_amdgcn_sched_barrier(0);                                                \
} while (0)
#define BAR() asm volatile("s_barrier" ::: "memory")

    // -------- prologue: tile0 full (8 loads) + tile1 {A-h0,B-h0,B-h1} (6 loads) ----
    {
        char* a0 = sm;                  // buf0 A
        char* b0 = sm + 32768;          // buf0 B
        char* a1 = sm + 65536;          // buf1 A
        char* b1 = sm + 65536 + 32768;  // buf1 B
        STAGE_HT(Abase, 0, 0, a0);
        STAGE_HT(Abase, 0, 1, a0 + 16384);
        STAGE_HT(Bbase, 0, 0, b0);
        STAGE_HT(Bbase, 0, 1, b0 + 16384);
        STAGE_HT(Abase, 1, 0, a1);
        STAGE_HT(Bbase, 1, 0, b1);
        STAGE_HT(Bbase, 1, 1, b1 + 16384);
        asm volatile("s_waitcnt vmcnt(6)" ::: "memory");   // tile0's 8 landed
        BAR();
        LD_A(af0, sm, 0, 0);            // LO0(0) fragments: A-h0 ks0
        LD_B(bv0, sm + 32768, 0);       //                   B    ks0
    }

    const int NT = K / 64;
    for (int t = 0; t < NT; ++t) {
        char* ldsA  = sm + (t & 1) * 65536;
        char* ldsB  = ldsA + 32768;
        char* ldsAn = sm + ((t & 1) ^ 1) * 65536;
        char* ldsBn = ldsAn + 32768;

        // ---- LO0: issue HI0's A-frags; stage A-h1(t+1); MFMA rows 0-3 ----------
        LD_A(af1, ldsA, 1, 0);
        if (t + 1 < NT) STAGE_HT(Abase, t + 1, 1, ldsAn + 16384);
        MFMA16(0, af0, bv0);
        BAR();

        // ---- HI0: issue LO1's frags; MFMA rows 4-7 -----------------------------
        LD_A(af0, ldsA, 0, 1);
        LD_B(bv1, ldsB, 1);
        MFMA16(4, af1, bv0);
        BAR();

        // ---- LO1: issue HI1's A-frags; MFMA rows 0-3; vmcnt(2) BEFORE barrier:
        //      oldest 6 = HI1(t-1)'s stages -> tile t+1 h0/B valid past this bar.
        LD_A(af1, ldsA, 1, 1);
        MFMA16(0, af0, bv1);
        asm volatile("s_waitcnt vmcnt(2)" ::: "memory");
        BAR();

        // ---- HI1: read t+1 frags (af0/bv0) from idle buf; stage t+2 h0/B into
        //      current buf (its last reads lgkm-completed before LO1's barrier);
        //      MFMA rows 4-7; vmcnt(6) BEFORE barrier: oldest 2 = A-h1(t+1).
        if (t + 1 < NT) {
            LD_A(af0, ldsAn, 0, 0);
            LD_B(bv0, ldsBn, 0);
        }
        if (t + 2 < NT) {
            STAGE_HT(Abase, t + 2, 0, ldsA);
            STAGE_HT(Bbase, t + 2, 0, ldsB);
            STAGE_HT(Bbase, t + 2, 1, ldsB + 16384);
            MFMA16(4, af1, bv1);
            asm volatile("s_waitcnt vmcnt(6)" ::: "memory");
        } else {
            MFMA16(4, af1, bv1);
            asm volatile("s_waitcnt vmcnt(0)" ::: "memory");
        }
        BAR();
    }

    // -------- epilogue: C/D layout col=lane&15, row=(lane>>4)*4+reg ----------------
    const int erow = (lane >> 4) * 4;
    const int ecol = lane & 15;
#pragma unroll
    for (int a = 0; a < 8; ++a)
#pragma unroll
        for (int c = 0; c < 4; ++c)
#pragma unroll
            for (int r = 0; r < 4; ++r) {
                long row = trow0 + (a >> 2) * 128 + wm * 64 + (a & 3) * 16 + erow + r;
                long col = tcol0 + (c >> 1) * 128 + wn * 32 + (c & 1) * 16 + ecol;
                C[row * N + col] = acc[a][c][r] * scale;
            }
#undef LD_A
#undef LD_B
#undef MFMA16
#undef BAR
#undef STAGE_HT
}

// -----------------------------------------------------------------------------------
extern "C" void kernel_launch(void* const* d_in, const int* in_sizes, int n_in,
                              void* d_out, int out_size, void* d_ws, size_t ws_size,
                              hipStream_t stream) {
    const int*   x    = (const int*)d_in[0];
    const float* emb  = (const float*)d_in[1];
    const float* wq   = (const float*)d_in[2];
    const float* wk   = (const float*)d_in[3];
    const float* wv   = (const float*)d_in[4];
    const float* wo   = (const float*)d_in[5];
    const float* wout = (const float*)d_in[6];
    float* logits = (float*)d_out;

    char* ws = (char*)d_ws;
    size_t off = 0;
    auto alloc = [&](size_t bytes) {
        char* p = ws + off;
        off += (bytes + 255) & ~(size_t)255;
        return p;
    };
    bf16_t* hb    = (bf16_t*)alloc((size_t)BT * DIM * 2);
    bf16_t* qb    = (bf16_t*)alloc((size_t)BT * DIM * 2);
    bf16_t* kb    = (bf16_t*)alloc((size_t)BT * DIM * 2);
    bf16_t* vtb   = (bf16_t*)alloc((size_t)BATCH * DIM * SEQ * 2);
    bf16_t* attnb = (bf16_t*)alloc((size_t)BATCH * SEQ * SEQ * 2);
    bf16_t* o1b   = (bf16_t*)alloc((size_t)BT * DIM * 2);
    bf16_t* o2b   = (bf16_t*)alloc((size_t)BT * DIM * 2);
    bf16_t* wqb   = (bf16_t*)alloc((size_t)DIM * DIM * 2);
    bf16_t* wkb   = (bf16_t*)alloc((size_t)DIM * DIM * 2);
    bf16_t* wvb   = (bf16_t*)alloc((size_t)DIM * DIM * 2);
    bf16_t* wob   = (bf16_t*)alloc((size_t)DIM * DIM * 2);
    bf16_t* woutb = (bf16_t*)alloc((size_t)VOCAB * DIM * 2);

    {
        int n4 = DIM * DIM / 4;
        cast_f32_to_bf16<<<n4 / 256, 256, 0, stream>>>(wq, wqb, n4);
        cast_f32_to_bf16<<<n4 / 256, 256, 0, stream>>>(wk, wkb, n4);
        cast_f32_to_bf16<<<n4 / 256, 256, 0, stream>>>(wv, wvb, n4);
        cast_f32_to_bf16<<<n4 / 256, 256, 0, stream>>>(wo, wob, n4);
        int n4o = VOCAB * DIM / 4;
        cast_f32_to_bf16<<<n4o / 256, 256, 0, stream>>>(wout, woutb, n4o);
    }

    embed_gather<<<BT, 256, 0, stream>>>(x, emb, hb);

    dim3 blk(256);
    gemm_bt<0, bf16_t><<<dim3(DIM / 128, BT / 128, 1), blk, 0, stream>>>(
        hb, wqb, qb, BT, DIM, DIM, 0, 0, 0, 0.01f);
    gemm_bt<0, bf16_t><<<dim3(DIM / 128, BT / 128, 1), blk, 0, stream>>>(
        hb, wkb, kb, BT, DIM, DIM, 0, 0, 0, 0.01f);
    gemm_bt<0, bf16_t><<<dim3(SEQ / 128, DIM / 128, BATCH), blk, 0, stream>>>(
        wvb, hb, vtb, DIM, SEQ, DIM, 0, (long)SEQ * DIM, (long)DIM * SEQ, 0.1f);
    gemm_bt<1, bf16_t><<<dim3(SEQ / 128, SEQ / 128, BATCH), blk, 0, stream>>>(
        qb, kb, attnb, SEQ, SEQ, DIM,
        (long)SEQ * DIM, (long)SEQ * DIM, (long)SEQ * SEQ, 0.01f);
    gemm_bt<0, bf16_t><<<dim3(DIM / 128, SEQ / 128, BATCH), blk, 0, stream>>>(
        attnb, vtb, o1b, SEQ, DIM, SEQ,
        (long)SEQ * SEQ, (long)DIM * SEQ, (long)SEQ * DIM, 0.01f);
    gemm_bt<0, bf16_t><<<dim3(DIM / 128, BT / 128, 1), blk, 0, stream>>>(
        o1b, wob, o2b, BT, DIM, DIM, 0, 0, 0, 0.1f);

    // logits: 256x256 pipelined; grid 1-D = 32 * 125 = 4000 blocks x 512 threads
    gemm_bt_256<<<(BT / 256) * (VOCAB / 256), 512, 0, stream>>>(
        o2b, woutb, logits, VOCAB, DIM, 1.0f);
}

// Round 12
// 921.345 us; speedup vs baseline: 1.9206x; 1.9206x over previous
//
#include <hip/hip_runtime.h>

// FHETinyGPT forward: emb-gather -> q/k/v proj -> QK^T+poly-act -> PV -> wo -> logits.
// Small/medium matmuls: m97-structure gemm_bt (128x128, BK=32, 4 waves).
// Logits + QK^T: 256x256 8-wave pipelined kernel, R8-verified schedule (in-phase
// ds_reads, fine-grained compiler lgkm waits, one barrier per phase, producer-side
// counted vmcnt). R12: reverted the R9-R11 cross-phase register ping-pong (R11
// falsified the launch-bounds theory: (512,1) == (512,2) byte-identical counters;
// the doubled fragment sets themselves cause scratch traffic: +0.4GB WRITE,
// MfmaUtil 15%). gemm_bt_256 is now templated <ACT, SWZ, CT> with batch strides:
//   SWZ=0: logits grid (nMt=32): tm = (lin&7)*4 + ((lin>>3)&3), tn = lin>>5
//   SWZ=1: QK^T grid (nMt=8 per batch): tm = lin&7, tn = lin>>3; z = batch
// QK^T fits 256 blocks = 1/CU exactly (M=N=2048, 4 batches) — the only mid-GEMM
// whose 256^2 grid saturates the chip; others stay m97 (128 blocks would idle
// half the CUs).

typedef __bf16 bf16_t;
typedef __bf16 bf16x8 __attribute__((ext_vector_type(8)));
typedef __bf16 bf16x4 __attribute__((ext_vector_type(4)));
typedef float  f32x4  __attribute__((ext_vector_type(4)));

#define VOCAB 32000
#define DIM   1024
#define BATCH 4
#define SEQ   2048
#define BT    (BATCH*SEQ)   // 8192

__device__ __forceinline__ void gload_lds16(const void* g, void* l) {
    __builtin_amdgcn_global_load_lds(
        (const __attribute__((address_space(1))) void*)g,
        (__attribute__((address_space(3))) void*)l,
        16, 0, 0);
}

// ---------------- weight cast f32 -> bf16 ------------------------------------------
__global__ void cast_f32_to_bf16(const float* __restrict__ in, bf16_t* __restrict__ out, int n4) {
    int i = blockIdx.x * blockDim.x + threadIdx.x;
    if (i < n4) {
        float4 v = ((const float4*)in)[i];
        bf16x4 o;
        o.x = (bf16_t)v.x; o.y = (bf16_t)v.y; o.z = (bf16_t)v.z; o.w = (bf16_t)v.w;
        ((bf16x4*)out)[i] = o;
    }
}

// ---------------- h = emb_w[x] * 0.01 -> bf16 [BT, DIM] ----------------------------
__global__ void embed_gather(const int* __restrict__ x, const float* __restrict__ emb,
                             bf16_t* __restrict__ h) {
    const int tok = blockIdx.x;
    const int row = x[tok];
    const float4* src = (const float4*)(emb + (long)row * DIM);
    bf16x4* dst = (bf16x4*)(h + (long)tok * DIM);
    int j = threadIdx.x;
    float4 v = src[j];
    bf16x4 o;
    o.x = (bf16_t)(v.x * 0.01f); o.y = (bf16_t)(v.y * 0.01f);
    o.z = (bf16_t)(v.z * 0.01f); o.w = (bf16_t)(v.w * 0.01f);
    dst[j] = o;
}

// ---------------- gemm_bt (m97-structure, for the small/medium matmuls) ------------
template<int ACT, typename CT>
__global__ __launch_bounds__(256) void gemm_bt(
    const bf16_t* __restrict__ A, const bf16_t* __restrict__ B, CT* __restrict__ C,
    int M, int N, int K, long sA, long sB, long sC, float scale)
{
    __shared__ __align__(16) bf16_t lsA[128 * 32];
    __shared__ __align__(16) bf16_t lsB[128 * 32];

    const int bz = blockIdx.z;
    A += (long)bz * sA;  B += (long)bz * sB;  C += (long)bz * sC;

    const int tm = blockIdx.y, tn = blockIdx.x;
    const int t = threadIdx.x;
    const int lane = t & 63, wave = t >> 6;
    const int wm = (wave >> 1) * 64;
    const int wn = (wave & 1) * 64;

    const int srow = t >> 2;
    const int scol = (t & 3) * 8;
    const bf16_t* gA = A + (long)(tm * 128 + srow) * K + scol;
    const bf16_t* gB = B + (long)(tn * 128 + srow) * K + scol;
    bf16_t* lA = &lsA[srow * 32 + scol];
    bf16_t* lB = &lsB[srow * 32 + scol];

    f32x4 acc[4][4];
#pragma unroll
    for (int i = 0; i < 4; ++i)
#pragma unroll
        for (int j = 0; j < 4; ++j)
            acc[i][j] = (f32x4){0.f, 0.f, 0.f, 0.f};

    const int arow = lane & 15;
    const int acol = (lane >> 4) * 8;

    for (int k0 = 0; k0 < K; k0 += 32) {
        __syncthreads();
        gload_lds16(gA + k0,                lA);
        gload_lds16(gA + k0 + 64 * (long)K, lA + 64 * 32);
        gload_lds16(gB + k0,                lB);
        gload_lds16(gB + k0 + 64 * (long)K, lB + 64 * 32);
        __syncthreads();

        bf16x8 af[4], bfr[4];
#pragma unroll
        for (int i = 0; i < 4; ++i) {
            af[i]  = *(const bf16x8*)&lsA[(wm + i * 16 + arow) * 32 + acol];
            bfr[i] = *(const bf16x8*)&lsB[(wn + i * 16 + arow) * 32 + acol];
        }
#pragma unroll
        for (int i = 0; i < 4; ++i)
#pragma unroll
            for (int j = 0; j < 4; ++j)
                acc[i][j] = __builtin_amdgcn_mfma_f32_16x16x32_bf16(af[i], bfr[j], acc[i][j], 0, 0, 0);
    }

    const int crow0 = tm * 128 + wm + (lane >> 4) * 4;
    const int ccol0 = tn * 128 + wn + (lane & 15);
#pragma unroll
    for (int i = 0; i < 4; ++i)
#pragma unroll
        for (int j = 0; j < 4; ++j)
#pragma unroll
            for (int r = 0; r < 4; ++r) {
                float s = acc[i][j][r] * scale;
                if (ACT) s = s * s * 0.1f + s * 0.1f;
                C[(long)(crow0 + i * 16 + r) * N + (ccol0 + j * 16)] = (CT)s;
            }
}

// ---------------- 256x256 pipelined GEMM: C[M,N] = epi(scale*A[M,K] @ B[N,K]^T) ----
// R8-verified schedule. Requires N % 256 == 0, K % 64 == 0, and a grid matching
// SWZ: SWZ=0 -> 1-D grid of 32*(N/256) blocks (M == 8192, logits);
//      SWZ=1 -> grid (64, 1, BATCH) with M == N == 2048 per batch (QK^T).
template<int ACT, int SWZ, typename CT>
__global__ __launch_bounds__(512, 2) void gemm_bt_256(
    const bf16_t* __restrict__ A, const bf16_t* __restrict__ B, CT* __restrict__ C,
    int N, int K, long sA, long sB, long sC, float scale)
{
    __shared__ __align__(16) char smem[131072];   // 2buf x (A 32KB + B 32KB)
    char* const sm = smem;

    const int bz = blockIdx.z;
    A += (long)bz * sA;  B += (long)bz * sB;  C += (long)bz * sC;

    // XCD band swizzle (dispatch lin%8 = XCD for both grids: 64 % 8 == 0)
    const int lin = blockIdx.x;
    int tm, tn;
    if (SWZ == 0) { const int xcd = lin & 7, jj = lin >> 3; tm = xcd * 4 + (jj & 3); tn = jj >> 2; }
    else          { tm = lin & 7; tn = lin >> 3; }
    const long trow0 = (long)tm * 256, tcol0 = (long)tn * 256;

    const int tid  = threadIdx.x;
    const int lane = tid & 63;
    const int wave = tid >> 6;
    const int wm = wave >> 2;            // 0..1  (M sub-band within each 128-half)
    const int wn = wave & 3;             // 0..3
    const int lr = lane & 15;
    const int ko2 = (lane >> 4) * 16;    // byte offset of this lane's 16B k-chunk
    // swizzled per-thread byte offset within a 1KB subtile (involution on bits 4-5)
    const int rbase = lr * 64 + (ko2 ^ (((lr >> 1) & 3) << 4));

    // staging decode (R4-verified): physical slot o holds logical slot sigma(o)
    const int o0 = tid * 16, o1 = 8192 + tid * 16;
    int sr0, sc0, sr1, sc1;
    {
        int ol = o0 ^ (((o0 >> 7) & 3) << 4);
        sr0 = ((ol >> 10) >> 1) * 16 + ((ol >> 6) & 15);
        sc0 = ((ol >> 10) & 1) * 32 + ((ol & 63) >> 1);
        ol = o1 ^ (((o1 >> 7) & 3) << 4);
        sr1 = ((ol >> 10) >> 1) * 16 + ((ol >> 6) & 15);
        sc1 = ((ol >> 10) & 1) * 32 + ((ol & 63) >> 1);
    }

    const bf16_t* Abase = A + trow0 * K;
    const bf16_t* Bbase = B + tcol0 * K;

    // stage one half-tile (128 rows x 64 cols) of K-tile kt into LDS half at ldsh
#define STAGE_HT(gbase, kt, half, ldsh) do {                                          \
    gload_lds16((gbase) + (long)((half) * 128 + sr0) * K + ((kt) * 64 + sc0), (ldsh) + o0); \
    gload_lds16((gbase) + (long)((half) * 128 + sr1) * K + ((kt) * 64 + sc1), (ldsh) + o1); \
} while (0)

    f32x4 acc[8][4];
#pragma unroll
    for (int i = 0; i < 8; ++i)
#pragma unroll
        for (int j = 0; j < 4; ++j)
            acc[i][j] = (f32x4){0.f, 0.f, 0.f, 0.f};

    // P_LO(ks): read A-h0 frags + all 4 B-frags at K-step ks (first-use order),
    //           16 MFMA rows 0-3. P_HI(ks): read A-h1 frags, reuse bv_ regs,
    //           16 MFMA rows 4-7. Compiler emits fine-grained lgkmcnt per MFMA;
    //           sched_barrier(0) pins the cluster before the phase-end barrier.
#define PHASE_LO(ks, ...) do {                                                        \
    bf16x8 af_[4];                                                                    \
    af_[0] = *(const bf16x8*)(ldsA + ((wm * 4 + 0) * 2 + (ks)) * 1024 + rbase);       \
    _Pragma("unroll")                                                                 \
    for (int c_ = 0; c_ < 4; ++c_)                                                    \
        bv_[c_] = *(const bf16x8*)(ldsB + (c_ >> 1) * 16384 +                         \
                      ((wn * 2 + (c_ & 1)) * 2 + (ks)) * 1024 + rbase);               \
    _Pragma("unroll")                                                                 \
    for (int i_ = 1; i_ < 4; ++i_)                                                    \
        af_[i_] = *(const bf16x8*)(ldsA +                                             \
                      ((wm * 4 + i_) * 2 + (ks)) * 1024 + rbase);                     \
    __VA_ARGS__;                                                                      \
    __builtin_amdgcn_s_setprio(1);                                                    \
    _Pragma("unroll")                                                                 \
    for (int i_ = 0; i_ < 4; ++i_)                                                    \
        _Pragma("unroll")                                                             \
        for (int c_ = 0; c_ < 4; ++c_)                                                \
            acc[i_][c_] = __builtin_amdgcn_mfma_f32_16x16x32_bf16(                    \
                af_[i_], bv_[c_], acc[i_][c_], 0, 0, 0);                              \
    __builtin_amdgcn_s_setprio(0);                                                    \
    __builtin_amdgcn_sched_barrier(0);                                                \
    asm volatile("s_barrier" ::: "memory");                                           \
} while (0)

#define PHASE_HI(ks, ...) do {                                                        \
    bf16x8 af_[4];                                                                    \
    _Pragma("unroll")                                                                 \
    for (int i_ = 0; i_ < 4; ++i_)                                                    \
        af_[i_] = *(const bf16x8*)(ldsA + 16384 +                                     \
                      ((wm * 4 + i_) * 2 + (ks)) * 1024 + rbase);                     \
    __VA_ARGS__;                                                                      \
    __builtin_amdgcn_s_setprio(1);                                                    \
    _Pragma("unroll")                                                                 \
    for (int i_ = 0; i_ < 4; ++i_)                                                    \
        _Pragma("unroll")                                                             \
        for (int c_ = 0; c_ < 4; ++c_)                                                \
            acc[4 + i_][c_] = __builtin_amdgcn_mfma_f32_16x16x32_bf16(                \
                af_[i_], bv_[c_], acc[4 + i_][c_], 0, 0, 0);                          \
    __builtin_amdgcn_s_setprio(0);                                                    \
    __builtin_amdgcn_sched_barrier(0);                                                \
} while (0)

    // -------- prologue: K0 fully + K1 h0s; vmcnt(4) => K0 landed -------------------
    {
        char* a0 = sm;
        char* b0 = sm + 32768;
        char* a1 = sm + 65536;
        char* b1 = sm + 65536 + 32768;
        STAGE_HT(Abase, 0, 0, a0);
        STAGE_HT(Bbase, 0, 0, b0);
        STAGE_HT(Abase, 0, 1, a0 + 16384);
        STAGE_HT(Bbase, 0, 1, b0 + 16384);
        STAGE_HT(Abase, 1, 0, a1);
        STAGE_HT(Bbase, 1, 0, b1);
        asm volatile("s_waitcnt vmcnt(4)" ::: "memory");
        asm volatile("s_barrier" ::: "memory");
    }

    const int NT = K / 64;
    for (int t = 0; t < NT; ++t) {
        const int buf = t & 1;
        char* ldsA  = sm + buf * 65536;
        char* ldsB  = ldsA + 32768;
        char* ldsAn = sm + (buf ^ 1) * 65536;
        char* ldsBn = ldsAn + 32768;
        bf16x8 bv_[4];

        // P0: ks=0 rows 0-3; stage tile t+1's h1 halves into the idle buffer
        PHASE_LO(0,
              if (t + 1 < NT) {
                  STAGE_HT(Abase, t + 1, 1, ldsAn + 16384);
                  STAGE_HT(Bbase, t + 1, 1, ldsBn + 16384);
              });

        // P1: ks=0 rows 4-7 (B reused in regs)
        PHASE_HI(0, );
        asm volatile("s_barrier" ::: "memory");

        // P2: ks=1 rows 0-3 (last LDS reads of A-h0 and both B halves)
        PHASE_LO(1, );

        // P3: ks=1 rows 4-7; stage t+2 h0s into current buffer (freed by P2's
        // end barrier); counted wait covers all of tile t+1.
        PHASE_HI(1,
              if (t + 2 < NT) {
                  STAGE_HT(Abase, t + 2, 0, ldsA);
                  STAGE_HT(Bbase, t + 2, 0, ldsB);
              });
        if (t + 2 < NT) { asm volatile("s_waitcnt vmcnt(4)" ::: "memory"); }
        else            { asm volatile("s_waitcnt vmcnt(0)" ::: "memory"); }
        asm volatile("s_barrier" ::: "memory");
    }

    // -------- epilogue: C/D layout col=lane&15, row=(lane>>4)*4+reg ----------------
    const int erow = (lane >> 4) * 4;
    const int ecol = lane & 15;
#pragma unroll
    for (int a = 0; a < 8; ++a)
#pragma unroll
        for (int c = 0; c < 4; ++c)
#pragma unroll
            for (int r = 0; r < 4; ++r) {
                long row = trow0 + (a >> 2) * 128 + wm * 64 + (a & 3) * 16 + erow + r;
                long col = tcol0 + (c >> 1) * 128 + wn * 32 + (c & 1) * 16 + ecol;
                float s = acc[a][c][r] * scale;
                if (ACT) s = s * s * 0.1f + s * 0.1f;
                C[row * N + col] = (CT)s;
            }
#undef PHASE_LO
#undef PHASE_HI
#undef STAGE_HT
}

// -----------------------------------------------------------------------------------
extern "C" void kernel_launch(void* const* d_in, const int* in_sizes, int n_in,
                              void* d_out, int out_size, void* d_ws, size_t ws_size,
                              hipStream_t stream) {
    const int*   x    = (const int*)d_in[0];
    const float* emb  = (const float*)d_in[1];
    const float* wq   = (const float*)d_in[2];
    const float* wk   = (const float*)d_in[3];
    const float* wv   = (const float*)d_in[4];
    const float* wo   = (const float*)d_in[5];
    const float* wout = (const float*)d_in[6];
    float* logits = (float*)d_out;

    char* ws = (char*)d_ws;
    size_t off = 0;
    auto alloc = [&](size_t bytes) {
        char* p = ws + off;
        off += (bytes + 255) & ~(size_t)255;
        return p;
    };
    bf16_t* hb    = (bf16_t*)alloc((size_t)BT * DIM * 2);
    bf16_t* qb    = (bf16_t*)alloc((size_t)BT * DIM * 2);
    bf16_t* kb    = (bf16_t*)alloc((size_t)BT * DIM * 2);
    bf16_t* vtb   = (bf16_t*)alloc((size_t)BATCH * DIM * SEQ * 2);
    bf16_t* attnb = (bf16_t*)alloc((size_t)BATCH * SEQ * SEQ * 2);
    bf16_t* o1b   = (bf16_t*)alloc((size_t)BT * DIM * 2);
    bf16_t* o2b   = (bf16_t*)alloc((size_t)BT * DIM * 2);
    bf16_t* wqb   = (bf16_t*)alloc((size_t)DIM * DIM * 2);
    bf16_t* wkb   = (bf16_t*)alloc((size_t)DIM * DIM * 2);
    bf16_t* wvb   = (bf16_t*)alloc((size_t)DIM * DIM * 2);
    bf16_t* wob   = (bf16_t*)alloc((size_t)DIM * DIM * 2);
    bf16_t* woutb = (bf16_t*)alloc((size_t)VOCAB * DIM * 2);

    {
        int n4 = DIM * DIM / 4;
        cast_f32_to_bf16<<<n4 / 256, 256, 0, stream>>>(wq, wqb, n4);
        cast_f32_to_bf16<<<n4 / 256, 256, 0, stream>>>(wk, wkb, n4);
        cast_f32_to_bf16<<<n4 / 256, 256, 0, stream>>>(wv, wvb, n4);
        cast_f32_to_bf16<<<n4 / 256, 256, 0, stream>>>(wo, wob, n4);
        int n4o = VOCAB * DIM / 4;
        cast_f32_to_bf16<<<n4o / 256, 256, 0, stream>>>(wout, woutb, n4o);
    }

    embed_gather<<<BT, 256, 0, stream>>>(x, emb, hb);

    dim3 blk(256);
    gemm_bt<0, bf16_t><<<dim3(DIM / 128, BT / 128, 1), blk, 0, stream>>>(
        hb, wqb, qb, BT, DIM, DIM, 0, 0, 0, 0.01f);
    gemm_bt<0, bf16_t><<<dim3(DIM / 128, BT / 128, 1), blk, 0, stream>>>(
        hb, wkb, kb, BT, DIM, DIM, 0, 0, 0, 0.01f);
    gemm_bt<0, bf16_t><<<dim3(SEQ / 128, DIM / 128, BATCH), blk, 0, stream>>>(
        wvb, hb, vtb, DIM, SEQ, DIM, 0, (long)SEQ * DIM, (long)DIM * SEQ, 0.1f);

    // attn = fhe_act(0.01 * q[b] @ k[b]^T): 256^2 pipelined, 64 blocks x 4 batches
    gemm_bt_256<1, 1, bf16_t><<<dim3(64, 1, BATCH), 512, 0, stream>>>(
        qb, kb, attnb, SEQ, DIM,
        (long)SEQ * DIM, (long)SEQ * DIM, (long)SEQ * SEQ, 0.01f);

    gemm_bt<0, bf16_t><<<dim3(DIM / 128, SEQ / 128, BATCH), blk, 0, stream>>>(
        attnb, vtb, o1b, SEQ, DIM, SEQ,
        (long)SEQ * SEQ, (long)DIM * SEQ, (long)SEQ * DIM, 0.01f);
    gemm_bt<0, bf16_t><<<dim3(DIM / 128, BT / 128, 1), blk, 0, stream>>>(
        o1b, wob, o2b, BT, DIM, DIM, 0, 0, 0, 0.1f);

    // logits = o2 @ wout^T: 256^2 pipelined; 32*125 = 4000 blocks
    gemm_bt_256<0, 0, float><<<dim3((BT / 256) * (VOCAB / 256), 1, 1), 512, 0, stream>>>(
        o2b, woutb, logits, VOCAB, DIM, 0, 0, 0, 1.0f);
}